// Round 11
// baseline (196.804 us; speedup 1.0000x reference)
//
#include <hip/hip_runtime.h>
#include <math.h>

#define HDIM 768
#define RDIM 64
#define NEXP 8
#define NTOK 16384

typedef _Float16 half8 __attribute__((ext_vector_type(8)));
typedef float float4_t __attribute__((ext_vector_type(4)));

__device__ __forceinline__ float gelu_exact(float v) {
    return 0.5f * v * (1.0f + erff(v * 0.70710678118654752440f));
}

// ---------------------------------------------------------------------------
// prep (R6-proven, unchanged).
// ---------------------------------------------------------------------------
__global__ __launch_bounds__(256) void prep_kernel(
    const float* __restrict__ w1, const float* __restrict__ w2,
    const float* __restrict__ enc_w, const float* __restrict__ enc_b,
    const float* __restrict__ sw_w, const float* __restrict__ sw_b,
    _Float16* __restrict__ w1t, _Float16* __restrict__ w2t,
    float* __restrict__ wrt, float* __restrict__ brr)
{
    const int wid = blockIdx.x * 4 + (threadIdx.x >> 6);
    const int lane = threadIdx.x & 63;
    if (wid < 768) {
        const int e = wid / 96, k0 = (wid % 96) * 8;
        half8 o;
        #pragma unroll
        for (int j = 0; j < 8; j++)
            o[j] = (_Float16)w1[((size_t)(e * HDIM + k0 + j)) * RDIM + lane];
        *(half8*)(w1t + ((size_t)(e * RDIM + lane)) * HDIM + k0) = o;
    } else if (wid < 1536) {
        const int id = wid - 768;
        const int e = id / 96, rem = id % 96;
        const int n = (rem >> 3) * 64 + lane, k0 = (rem & 7) * 8;
        half8 o;
        #pragma unroll
        for (int j = 0; j < 8; j++)
            o[j] = (_Float16)w2[((size_t)(e * RDIM + k0 + j)) * HDIM + n];
        *(half8*)(w2t + ((size_t)(e * HDIM + n)) * RDIM + k0) = o;
    } else if (wid < 1632) {
        const int k = (wid - 1536) * 8 + (lane >> 3);
        const int e = lane & 7;
        float s = 0.0f;
        #pragma unroll 16
        for (int r = 0; r < RDIM; r++)
            s += enc_w[(size_t)k * RDIM + r] * sw_w[r * NEXP + e];
        wrt[e * HDIM + k] = s;
    } else if (wid == 1632) {
        if (lane < NEXP) {
            float s = sw_b[lane];
            #pragma unroll 16
            for (int r = 0; r < RDIM; r++)
                s += enc_b[r] * sw_w[r * NEXP + lane];
            brr[lane] = s;
        }
    }
}

// ---------------------------------------------------------------------------
// router v4 (R6-proven, unchanged).
// ---------------------------------------------------------------------------
__global__ __launch_bounds__(256, 4) void router_kernel(
    const float* __restrict__ x, const float* __restrict__ wrt,
    const float* __restrict__ brr, float* __restrict__ pmax,
    int* __restrict__ counts, int* __restrict__ lists)
{
    __shared__ __align__(16) float wrl[NEXP][772];
    __shared__ int lcnt[NEXP], gbase[NEXP];

    const int tid = threadIdx.x;
    #pragma unroll
    for (int i0 = 0; i0 < 6; i0++) {
        const int i = tid + i0 * 256;
        const int e = i / 192, k4 = (i % 192) * 4;
        *(float4*)&wrl[e][k4] = *(const float4*)(wrt + e * HDIM + k4);
    }
    if (tid < NEXP) lcnt[tid] = 0;

    const int wv = tid >> 6, lane = tid & 63;
    const int h = lane & 31, hw = lane >> 5;

    float br[8];
    #pragma unroll
    for (int e = 0; e < 8; e++) br[e] = brr[e];
    __syncthreads();

    int amv[2], lpv[2], tkv[2];
    #pragma unroll
    for (int it = 0; it < 2; it++) {
        const int tok = blockIdx.x * 16 + it * 8 + wv * 2 + hw;
        const float* xrow = x + (size_t)tok * HDIM;
        float4 xv[6];
        #pragma unroll
        for (int g = 0; g < 6; g++)
            xv[g] = *(const float4*)(xrow + g * 128 + h * 4);

        float acc[8];
        #pragma unroll
        for (int e = 0; e < 8; e++) acc[e] = 0.0f;
        #pragma unroll
        for (int e = 0; e < 8; e++) {
            #pragma unroll
            for (int g = 0; g < 6; g++) {
                const float4 w4 = *(const float4*)&wrl[e][g * 128 + h * 4];
                acc[e] = fmaf(xv[g].x, w4.x, acc[e]);
                acc[e] = fmaf(xv[g].y, w4.y, acc[e]);
                acc[e] = fmaf(xv[g].z, w4.z, acc[e]);
                acc[e] = fmaf(xv[g].w, w4.w, acc[e]);
            }
        }
        #pragma unroll
        for (int d = 1; d < 32; d <<= 1) {
            #pragma unroll
            for (int e = 0; e < 8; e++)
                acc[e] += __shfl_xor(acc[e], d);
        }
        float lg[8];
        lg[0] = acc[0] + br[0];
        float m = lg[0]; int am = 0;
        #pragma unroll
        for (int e = 1; e < 8; e++) {
            lg[e] = acc[e] + br[e];
            if (lg[e] > m) { m = lg[e]; am = e; }
        }
        float s = 0.0f;
        #pragma unroll
        for (int e = 0; e < 8; e++) s += expf(lg[e] - m);

        amv[it] = -1;
        if (h == 0) {
            pmax[tok] = 1.0f / s;
            amv[it] = am;
            lpv[it] = atomicAdd(&lcnt[am], 1);
            tkv[it] = tok;
        }
    }
    __syncthreads();
    if (tid < NEXP) gbase[tid] = atomicAdd(&counts[tid * 32], lcnt[tid]);
    __syncthreads();
    #pragma unroll
    for (int it = 0; it < 2; it++)
        if (amv[it] >= 0)
            lists[amv[it] * NTOK + gbase[amv[it]] + lpv[it]] = tkv[it];
}

// ---------------------------------------------------------------------------
// mm12 v5: cross-strip software pipeline (T14 async-stage split).
// R10 falsified the store theory: bytes ideal, all pipes idle -> the cap is
// the per-strip serial latency chain (lists->x, w1t, w2t rounds) with one
// strip per block and launch-synchronized phases. Fix: grid (8,64) = 2
// strips/block; xt double-buffered; at each strip top, write the REG-staged
// x (loaded during the previous strip's compute) to xt[buf], then issue the
// NEXT strip's global loads into regs before phase A. Staging latency hides
// under a full strip of MFMA+L2 work; lists->x chain leaves the critical
// path after strip 0. 2 barriers/strip; scatter stores (R9/R10: WRITE ideal
// either way). LDS 52.2KB (xt dbuf 48.5K + hl + tkl/pml dbuf) -> 3 blk/CU.
// ---------------------------------------------------------------------------
__global__ __launch_bounds__(256, 3) void mm12_kernel(
    const float* __restrict__ x, const _Float16* __restrict__ w1t,
    const float* __restrict__ b1, const _Float16* __restrict__ w2t,
    const float* __restrict__ b2, const float* __restrict__ pmax,
    const int* __restrict__ counts, const int* __restrict__ lists,
    float* __restrict__ out)
{
    __shared__ __align__(16) _Float16 xt[2][16][776];   // 49664 B
    __shared__ __align__(16) _Float16 hl[16][72];       //  2304 B
    __shared__ float pml[2][16];
    __shared__ int tkl[2][16];

    const int e = blockIdx.x;
    const int cnt = counts[e * 32];
    const int tid = threadIdx.x;
    const int wv = tid >> 6, lane = tid & 63;
    const int q = lane >> 4, c = lane & 15;

    int st = blockIdx.y;
    if (st * 16 >= cnt) return;

    // ---- prologue: issue strip-0 x loads into regs (1KB/instruction) ----
    float4 xv[12];
    {
        const int base = st * 16;
        const int nt = cnt - base;
        #pragma unroll
        for (int rr = 0; rr < 4; rr++) {
            const int row = wv * 4 + rr;
            const int tok = lists[e * NTOK + base + min(row, nt - 1)];
            const float* xr = x + (size_t)tok * HDIM;
            #pragma unroll
            for (int j = 0; j < 3; j++)
                xv[rr * 3 + j] = *(const float4*)(xr + j * 256 + lane * 4);
        }
    }

    int buf = 0;
    while (st * 16 < cnt) {
        const int base = st * 16;
        const int nt = cnt - base;

        if (tid < 16) {
            const int t = lists[e * NTOK + base + min(tid, nt - 1)];
            tkl[buf][tid] = t;
            pml[buf][tid] = pmax[t];
        }
        // ---- write reg-staged x -> xt[buf] (f16 pack) ----
        #pragma unroll
        for (int rr = 0; rr < 4; rr++) {
            const int row = wv * 4 + rr;
            #pragma unroll
            for (int j = 0; j < 3; j++) {
                float4 v = xv[rr * 3 + j];
                union { _Float16 hv[4]; unsigned long long u; } pk;
                pk.hv[0] = (_Float16)v.x; pk.hv[1] = (_Float16)v.y;
                pk.hv[2] = (_Float16)v.z; pk.hv[3] = (_Float16)v.w;
                *(unsigned long long*)&xt[buf][row][j * 256 + lane * 4] = pk.u;
            }
        }
        __syncthreads();

        // ---- issue NEXT strip's x loads (overlap with phase A+B below) ----
        const int nst = st + gridDim.y;
        if (nst * 16 < cnt) {
            const int nbase = nst * 16;
            const int nnt = cnt - nbase;
            #pragma unroll
            for (int rr = 0; rr < 4; rr++) {
                const int row = wv * 4 + rr;
                const int tok = lists[e * NTOK + nbase + min(row, nnt - 1)];
                const float* xr = x + (size_t)tok * HDIM;
                #pragma unroll
                for (int j = 0; j < 3; j++)
                    xv[rr * 3 + j] = *(const float4*)(xr + j * 256 + lane * 4);
            }
        }

        // ---- phase A: wave wv -> r-cols [wv*16,+16), K=768 from LDS ----
        {
            const _Float16* wbase =
                w1t + ((size_t)(e * RDIM + wv * 16 + c)) * HDIM + q * 8;
            float4_t acc = {0, 0, 0, 0};
            #pragma unroll 6
            for (int k0 = 0; k0 < HDIM; k0 += 32) {
                half8 a = *(const half8*)&xt[buf][c][k0 + q * 8];
                half8 b = *(const half8*)(wbase + k0);
                acc = __builtin_amdgcn_mfma_f32_16x16x32_f16(a, b, acc, 0, 0, 0);
            }
            const float b1v = b1[e * RDIM + wv * 16 + c];
            #pragma unroll
            for (int i = 0; i < 4; i++)
                hl[q * 4 + i][wv * 16 + c] = (_Float16)gelu_exact(acc[i] + b1v);
        }
        __syncthreads();

        // ---- phase B: wave wv -> n in [wv*192,+192); scatter store ----
        {
            half8 a0 = *(const half8*)&hl[c][q * 8];
            half8 a1 = *(const half8*)&hl[c][32 + q * 8];
            int tokv[4]; float pm[4]; bool ok[4];
            #pragma unroll
            for (int i = 0; i < 4; i++) {
                const int row = q * 4 + i;
                ok[i] = row < nt;
                tokv[i] = tkl[buf][row];
                pm[i] = pml[buf][row];
            }
            #pragma unroll 4
            for (int nf = 0; nf < 12; nf++) {
                const int n = wv * 192 + nf * 16 + c;
                const _Float16* wrow = w2t + ((size_t)(e * HDIM + n)) * RDIM;
                half8 b0  = *(const half8*)(wrow + q * 8);
                half8 b1h = *(const half8*)(wrow + 32 + q * 8);
                float4_t acc2 = {0, 0, 0, 0};
                acc2 = __builtin_amdgcn_mfma_f32_16x16x32_f16(a0, b0, acc2, 0, 0, 0);
                acc2 = __builtin_amdgcn_mfma_f32_16x16x32_f16(a1, b1h, acc2, 0, 0, 0);
                const float b2v = b2[e * HDIM + n];
                #pragma unroll
                for (int i = 0; i < 4; i++) {
                    if (ok[i])
                        out[(size_t)tokv[i] * HDIM + n] = (acc2[i] + b2v) * pm[i];
                }
            }
        }
        // no barrier here: next top writes xt[buf^1]/tkl[buf^1] (disjoint
        // from anything a lagging wave reads in phase B of buf), and the
        // hl rewrite in next phase A is fenced by the next barrier1.
        st = nst; buf ^= 1;
    }
}

extern "C" void kernel_launch(void* const* d_in, const int* in_sizes, int n_in,
                              void* d_out, int out_size, void* d_ws, size_t ws_size,
                              hipStream_t stream) {
    const float* x     = (const float*)d_in[0];
    const float* enc_w = (const float*)d_in[1];
    const float* enc_b = (const float*)d_in[2];
    const float* sw_w  = (const float*)d_in[3];
    const float* sw_b  = (const float*)d_in[4];
    const float* w1    = (const float*)d_in[5];
    const float* b1    = (const float*)d_in[6];
    const float* w2    = (const float*)d_in[7];
    const float* b2    = (const float*)d_in[8];
    float* out = (float*)d_out;

    // ws layout (~2.2 MB):
    //   [0,1K)          counts (8 ints, 128B stride)
    //   [1K,66560)      pmax 16384 f32
    //   [66560,590848)  lists 8*16384 i32
    //   [590848,...)    wrt (24K), brr (256B), w1t (768K), w2t (768K)
    char* p = (char*)d_ws;
    int*      counts = (int*)p;
    float*    pmax   = (float*)(p + 1024);
    int*      lists  = (int*)(p + 66560);
    float*    wrt    = (float*)(p + 590848);
    float*    brr    = (float*)(p + 615424);
    _Float16* w1t    = (_Float16*)(p + 615680);
    _Float16* w2t    = (_Float16*)(p + 1402112);

    hipMemsetAsync(d_ws, 0, 1024, stream);

    hipLaunchKernelGGL(prep_kernel, dim3(409), dim3(256), 0, stream,
                       w1, w2, enc_w, enc_b, sw_w, sw_b, w1t, w2t, wrt, brr);
    hipLaunchKernelGGL(router_kernel, dim3(NTOK / 16), dim3(256), 0, stream,
                       x, wrt, brr, pmax, counts, lists);
    hipLaunchKernelGGL(mm12_kernel, dim3(NEXP, 64), dim3(256), 0, stream,
                       x, w1t, b1, w2t, b2, pmax, counts, lists, out);
}